// Round 4
// baseline (358.347 us; speedup 1.0000x reference)
//
#include <hip/hip_runtime.h>
#include <hip/hip_bf16.h>
#include <math.h>

typedef unsigned short ushortT;
typedef __attribute__((ext_vector_type(8))) short short8;
typedef __attribute__((ext_vector_type(4))) float f32x4;

// Problem constants (fixed by the reference)
constexpr int NN   = 10000;    // nodes
constexpr int EE   = 160000;   // edges (before self-loops)
constexpr int ETOT = EE + NN;  // edges incl. self-loops
constexpr int NG   = 64;       // graphs
constexpr int HID  = 256;
constexpr int HEADS = 4;

__device__ __forceinline__ ushortT f2bf(float x) {
    __hip_bfloat16 h = __float2bfloat16(x);
    return *reinterpret_cast<ushortT*>(&h);
}
__device__ __forceinline__ float bf2f(ushortT x) {
    unsigned u = ((unsigned)x) << 16;
    return __uint_as_float(u);
}

// ---------------------------------------------------------------------------
// CSR build: histogram, scan, fill
// ---------------------------------------------------------------------------
__global__ void edge_count_kernel(const int* __restrict__ ei, int* __restrict__ cnt) {
    int e = blockIdx.x * blockDim.x + threadIdx.x;
    if (e >= ETOT) return;
    int dst = (e < EE) ? ei[EE + e] : (e - EE);
    atomicAdd(&cnt[dst], 1);
}

__global__ void scan_kernel(const int* __restrict__ cnt, int* __restrict__ row_ptr,
                            int* __restrict__ cursor) {
    __shared__ int part[256];
    int tid = threadIdx.x;
    const int chunk = (NN + 255) / 256;   // 40
    int s0 = tid * chunk;
    int s1 = min(NN, s0 + chunk);
    int sum = 0;
    for (int i = s0; i < s1; ++i) sum += cnt[i];
    part[tid] = sum;
    __syncthreads();
    for (int off = 1; off < 256; off <<= 1) {
        int v = (tid >= off) ? part[tid - off] : 0;
        __syncthreads();
        part[tid] += v;
        __syncthreads();
    }
    int run = (tid == 0) ? 0 : part[tid - 1];
    for (int i = s0; i < s1; ++i) {
        row_ptr[i] = run;
        cursor[i]  = run;
        run += cnt[i];
    }
    if (tid == 255) row_ptr[NN] = part[255];
}

__global__ void edge_fill_kernel(const int* __restrict__ ei, int* __restrict__ cursor,
                                 int* __restrict__ col_src) {
    int e = blockIdx.x * blockDim.x + threadIdx.x;
    if (e >= ETOT) return;
    int src, dst;
    if (e < EE) { src = ei[e]; dst = ei[EE + e]; }
    else        { src = dst = e - EE; }
    int pos = atomicAdd(&cursor[dst], 1);
    col_src[pos] = src;
}

// ---------------------------------------------------------------------------
// weight transpose-convert: Wt[n][kp] = bf16(W[k][n]), zero-pad k>=K
// ---------------------------------------------------------------------------
__global__ void convert_wt(const float* __restrict__ W, ushortT* __restrict__ Wt,
                           int K, int N, int Kp) {
    __shared__ float t[32][33];
    int n0 = blockIdx.x * 32, k0 = blockIdx.y * 32;
    int tx = threadIdx.x, ty = threadIdx.y;    // 32 x 8
    for (int i = ty; i < 32; i += 8) {
        int k = k0 + i, n = n0 + tx;
        t[i][tx] = (k < K && n < N) ? W[(size_t)k * N + n] : 0.f;
    }
    __syncthreads();
    for (int i = ty; i < 32; i += 8) {
        int n = n0 + i, kp = k0 + tx;
        if (n < N && kp < Kp) Wt[(size_t)n * Kp + kp] = f2bf(t[tx][i]);
    }
}

__global__ void convert_atom(const float* __restrict__ a, ushortT* __restrict__ out) {
    // [NN][23] fp32 -> [NN][32] bf16 zero-padded
    int idx = blockIdx.x * 256 + threadIdx.x;
    if (idx >= NN * 32) return;
    int n = idx >> 5, k = idx & 31;
    out[idx] = (k < 23) ? f2bf(a[n * 23 + k]) : (ushortT)0;
}

// ---------------------------------------------------------------------------
// bf16 MFMA GEMM: C[M,N] bf16 = A[M,K]bf16 @ Bt[N,K]bf16^T
// tile 128x128x32, 256 threads = 4 waves (2x2), per-wave 64x64 (4x4 frags)
// Epilogue additionally computes partial attention dots:
//   a_s[row,head] += sum_cols acc*att_s[col],  a_d likewise (atomicAdd).
// Each wave's 64 cols lie within ONE head (HID=256, col groups of 64).
// ---------------------------------------------------------------------------
__device__ __forceinline__ void gload_lds16(const ushortT* gsrc, ushortT* ldst) {
    __builtin_amdgcn_global_load_lds(
        (const __attribute__((address_space(1))) unsigned int*)gsrc,
        (__attribute__((address_space(3))) unsigned int*)ldst, 16, 0, 0);
}

__global__ __launch_bounds__(256, 2) void gemm_bf16(const ushortT* __restrict__ A,
                                                    const ushortT* __restrict__ Bt,
                                                    ushortT* __restrict__ C,
                                                    const float* __restrict__ att_s,
                                                    const float* __restrict__ att_d,
                                                    float* __restrict__ a_sp,
                                                    float* __restrict__ a_dp,
                                                    int adim,
                                                    int M, int N, int K) {
    __shared__ ushortT lds[2][2][128][32];   // [buf][A/B][row][k]  32 KB
    const int tid  = threadIdx.x;
    const int lane = tid & 63, w = tid >> 6;
    const int wm = w >> 1, wn = w & 1;
    const int row0 = blockIdx.y * 128;
    const int col0 = blockIdx.x * 128;
    const int nt = K >> 5;

    auto stage = [&](int buf, int t) {
        int k0 = t << 5;
        #pragma unroll
        for (int i = 0; i < 2; ++i) {
            int gbase = (w * 2 + i) * 64;          // granule base (16B units)
            int g = gbase + lane;
            int row = g >> 2;
            int sw = (row & 3) ^ ((row >> 2) & 3);
            int koff = (g & 3) ^ sw;
            int arow = min(row0 + row, M - 1);
            gload_lds16(A + (size_t)arow * K + k0 + koff * 8,
                        &lds[buf][0][0][0] + gbase * 8);
            int brow = col0 + row;                 // always < N (N % 128 == 0)
            gload_lds16(Bt + (size_t)brow * K + k0 + koff * 8,
                        &lds[buf][1][0][0] + gbase * 8);
        }
    };

    f32x4 acc[4][4] = {};
    const int lr = lane & 15, lk = lane >> 4;

    stage(0, 0);
    for (int t = 0; t < nt; ++t) {
        int buf = t & 1;
        __syncthreads();                 // staged data for buf is ready
        if (t + 1 < nt) stage(buf ^ 1, t + 1);
        short8 a[4], b[4];
        const ushortT* baseA = &lds[buf][0][0][0];
        const ushortT* baseB = &lds[buf][1][0][0];
        #pragma unroll
        for (int m = 0; m < 4; ++m) {
            int row = wm * 64 + m * 16 + lr;
            int sw = (row & 3) ^ ((row >> 2) & 3);
            a[m] = *(const short8*)(baseA + row * 32 + ((lk ^ sw) * 8));
        }
        #pragma unroll
        for (int n = 0; n < 4; ++n) {
            int row = wn * 64 + n * 16 + lr;
            int sw = (row & 3) ^ ((row >> 2) & 3);
            b[n] = *(const short8*)(baseB + row * 32 + ((lk ^ sw) * 8));
        }
        #pragma unroll
        for (int m = 0; m < 4; ++m)
            #pragma unroll
            for (int n = 0; n < 4; ++n)
                acc[m][n] = __builtin_amdgcn_mfma_f32_16x16x32_bf16(a[m], b[n], acc[m][n], 0, 0, 0);
    }

    // epilogue: C/D layout col=lane&15, row=(lane>>4)*4+reg
    #pragma unroll
    for (int m = 0; m < 4; ++m) {
        #pragma unroll
        for (int n = 0; n < 4; ++n) {
            int col = col0 + wn * 64 + n * 16 + lr;
            #pragma unroll
            for (int j = 0; j < 4; ++j) {
                int rowg = row0 + wm * 64 + m * 16 + lk * 4 + j;
                if (rowg < M) C[(size_t)rowg * N + col] = f2bf(acc[m][n][j]);
            }
        }
    }

    // fused attention partial dots
    {
        const int colbase = col0 + wn * 64;
        const int head = colbase >> 8;    // all 64 wave cols within one head
        float s_att[4], d_att[4];
        #pragma unroll
        for (int n = 0; n < 4; ++n) {
            int col = colbase + n * 16 + lr;
            s_att[n] = att_s[col];
            d_att[n] = att_d[col];
        }
        #pragma unroll
        for (int m = 0; m < 4; ++m) {
            #pragma unroll
            for (int j = 0; j < 4; ++j) {
                float ps = acc[m][0][j] * s_att[0] + acc[m][1][j] * s_att[1]
                         + acc[m][2][j] * s_att[2] + acc[m][3][j] * s_att[3];
                float pd = acc[m][0][j] * d_att[0] + acc[m][1][j] * d_att[1]
                         + acc[m][2][j] * d_att[2] + acc[m][3][j] * d_att[3];
                #pragma unroll
                for (int off = 1; off < 16; off <<= 1) {
                    ps += __shfl_xor(ps, off);
                    pd += __shfl_xor(pd, off);
                }
                if (lr == 0) {
                    int rowg = row0 + wm * 64 + m * 16 + lk * 4 + j;
                    if (rowg < M) {
                        atomicAdd(a_sp + (size_t)rowg * adim + head, ps);
                        atomicAdd(a_dp + (size_t)rowg * adim + head, pd);
                    }
                }
            }
        }
    }
}

// ---------------------------------------------------------------------------
// GAT aggregation, one WAVE per dst node (4 waves/block, no __syncthreads).
// No max-shift (exp(l) directly; the shift cancels in alpha=e/sum(e), and
// |l| is O(15) here so no overflow). Gathers bf16 h rows: lane owns C/64
// channels; weights broadcast via per-wave LDS slab (in-order DS per wave).
// ---------------------------------------------------------------------------
__global__ __launch_bounds__(256) void gat_aggregate_w(const ushortT* __restrict__ hfeat,
                                                       const float* __restrict__ a_s,
                                                       const float* __restrict__ a_d,
                                                       const int* __restrict__ row_ptr,
                                                       const int* __restrict__ col_src,
                                                       const float* __restrict__ bias,
                                                       float* __restrict__ outf,
                                                       ushortT* __restrict__ out16,
                                                       int heads) {
    const int wv = threadIdx.x >> 6, lane = threadIdx.x & 63;
    const int i = blockIdx.x * 4 + wv;
    if (i >= NN) return;
    const int C = heads * HID;          // 1024 or 256
    const int nch = C >> 6;             // 16 or 4 channels per lane
    const int c0 = lane * nch;
    const int hh = c0 >> 8;             // my head (0..3 or 0)
    const int start = row_ptr[i], end = row_ptr[i + 1];

    __shared__ float wsh[4][64][4];     // [wave][edge][head]
    __shared__ int   ssh[4][64];

    float acc[16];
    #pragma unroll
    for (int c = 0; c < 16; ++c) acc[c] = 0.f;
    float den4[4] = {0.f, 0.f, 0.f, 0.f};

    for (int cb = start; cb < end; cb += 64) {
        int clen = min(64, end - cb);
        if (lane < clen) {
            int s = col_src[cb + lane];
            ssh[wv][lane] = s;
            if (heads == 4) {
                float4 as4 = *(const float4*)(a_s + (size_t)s * 4);
                float4 ad4 = *(const float4*)(a_d + (size_t)i * 4);
                float l0 = as4.x + ad4.x; l0 = (l0 >= 0.f) ? l0 : 0.2f * l0;
                float l1 = as4.y + ad4.y; l1 = (l1 >= 0.f) ? l1 : 0.2f * l1;
                float l2 = as4.z + ad4.z; l2 = (l2 >= 0.f) ? l2 : 0.2f * l2;
                float l3 = as4.w + ad4.w; l3 = (l3 >= 0.f) ? l3 : 0.2f * l3;
                float w0 = expf(l0), w1 = expf(l1), w2 = expf(l2), w3 = expf(l3);
                *reinterpret_cast<float4*>(&wsh[wv][lane][0]) = make_float4(w0, w1, w2, w3);
                den4[0] += w0; den4[1] += w1; den4[2] += w2; den4[3] += w3;
            } else {
                float l0 = a_s[s] + a_d[i]; l0 = (l0 >= 0.f) ? l0 : 0.2f * l0;
                float w0 = expf(l0);
                wsh[wv][lane][0] = w0;
                den4[0] += w0;
            }
        }
        __builtin_amdgcn_wave_barrier();   // keep compiler from reordering DS ops
        if (nch == 16) {
            for (int e = 0; e < clen; ++e) {
                int s = ssh[wv][e];
                float wgt = wsh[wv][e][hh];
                const ushortT* p = hfeat + (size_t)s * C + c0;
                short8 v0 = *(const short8*)p;
                short8 v1 = *(const short8*)(p + 8);
                #pragma unroll
                for (int j = 0; j < 8; ++j) {
                    acc[j]     += wgt * bf2f((ushortT)v0[j]);
                    acc[8 + j] += wgt * bf2f((ushortT)v1[j]);
                }
            }
        } else {
            for (int e = 0; e < clen; ++e) {
                int s = ssh[wv][e];
                float wgt = wsh[wv][e][0];
                const ushortT* p = hfeat + (size_t)s * C + c0;
                ushort4 v = *(const ushort4*)p;
                acc[0] += wgt * bf2f(v.x); acc[1] += wgt * bf2f(v.y);
                acc[2] += wgt * bf2f(v.z); acc[3] += wgt * bf2f(v.w);
            }
        }
        __builtin_amdgcn_wave_barrier();   // before next chunk overwrites slabs
    }

    // denominator: butterfly over the full wave
    if (heads == 4) {
        #pragma unroll
        for (int off = 1; off < 64; off <<= 1) {
            den4[0] += __shfl_xor(den4[0], off);
            den4[1] += __shfl_xor(den4[1], off);
            den4[2] += __shfl_xor(den4[2], off);
            den4[3] += __shfl_xor(den4[3], off);
        }
    } else {
        #pragma unroll
        for (int off = 1; off < 64; off <<= 1) den4[0] += __shfl_xor(den4[0], off);
    }
    float den = den4[0];
    if (heads == 4) {
        den = (hh == 0) ? den4[0] : (hh == 1) ? den4[1] : (hh == 2) ? den4[2] : den4[3];
    }
    float inv = 1.f / (den + 1e-16f);

    if (heads == 4) {
        ushortT pk[16];
        #pragma unroll
        for (int c = 0; c < 16; ++c) {
            float v = acc[c] * inv + bias[c0 + c];
            v = (v > 0.f) ? v : expm1f(v);
            pk[c] = f2bf(v);
        }
        *reinterpret_cast<short8*>(out16 + (size_t)i * C + c0)     = *reinterpret_cast<short8*>(&pk[0]);
        *reinterpret_cast<short8*>(out16 + (size_t)i * C + c0 + 8) = *reinterpret_cast<short8*>(&pk[8]);
    } else {
        float4 o;
        float v0 = acc[0] * inv + bias[c0 + 0]; o.x = (v0 > 0.f) ? v0 : expm1f(v0);
        float v1 = acc[1] * inv + bias[c0 + 1]; o.y = (v1 > 0.f) ? v1 : expm1f(v1);
        float v2 = acc[2] * inv + bias[c0 + 2]; o.z = (v2 > 0.f) ? v2 : expm1f(v2);
        float v3 = acc[3] * inv + bias[c0 + 3]; o.w = (v3 > 0.f) ? v3 : expm1f(v3);
        *reinterpret_cast<float4*>(outf + (size_t)i * C + c0) = o;
    }
}

// ---------------------------------------------------------------------------
// global mean pool + MLP head. One block (256 thr) per graph.
// ---------------------------------------------------------------------------
__global__ void pool_mlp(const float* __restrict__ x,      // [NN, HID]
                         const int* __restrict__ batch,
                         const float* __restrict__ fc1_w,  // [HID, 128]
                         const float* __restrict__ fc1_b,  // [128]
                         const float* __restrict__ fc2_w,  // [128]
                         const float* __restrict__ fc2_b,  // [1]
                         float* __restrict__ out) {        // [NG + NG*HID]
    int g = blockIdx.x, tid = threadIdx.x;   // 256 threads
    int lo = 0, hi = NN;
    while (lo < hi) { int mid = (lo + hi) >> 1; if (batch[mid] < g) lo = mid + 1; else hi = mid; }
    int s0 = lo;
    lo = 0; hi = NN;
    while (lo < hi) { int mid = (lo + hi) >> 1; if (batch[mid] < g + 1) lo = mid + 1; else hi = mid; }
    int s1 = lo;

    float acc = 0.f;
    for (int n = s0; n < s1; ++n) acc += x[(size_t)n * HID + tid];
    float cnt = (float)(s1 - s0);
    float feat = acc / fmaxf(cnt, 1.f);
    out[NG + g * HID + tid] = feat;

    __shared__ float fsh[HID];
    fsh[tid] = feat;
    __syncthreads();
    __shared__ float r2[128];
    if (tid < 128) {
        float a = fc1_b[tid];
        for (int c = 0; c < HID; ++c) a += fsh[c] * fc1_w[c * 128 + tid];
        a = fmaxf(a, 0.f);
        r2[tid] = a * fc2_w[tid];
    }
    __syncthreads();
    for (int s2 = 64; s2 > 0; s2 >>= 1) {
        if (tid < s2) r2[tid] += r2[tid + s2];
        __syncthreads();
    }
    if (tid == 0) out[g] = r2[0] + fc2_b[0];
}

// ---------------------------------------------------------------------------
extern "C" void kernel_launch(void* const* d_in, const int* in_sizes, int n_in,
                              void* d_out, int out_size, void* d_ws, size_t ws_size,
                              hipStream_t stream) {
    const float* atom  = (const float*)d_in[0];
    const int*   ei    = (const int*)  d_in[1];
    const int*   batch = (const int*)  d_in[2];
    const float* W1  = (const float*)d_in[3];
    const float* as1 = (const float*)d_in[4];
    const float* ad1 = (const float*)d_in[5];
    const float* b1  = (const float*)d_in[6];
    const float* W2  = (const float*)d_in[7];
    const float* as2 = (const float*)d_in[8];
    const float* ad2 = (const float*)d_in[9];
    const float* b2  = (const float*)d_in[10];
    const float* W3  = (const float*)d_in[11];
    const float* as3 = (const float*)d_in[12];
    const float* ad3 = (const float*)d_in[13];
    const float* b3  = (const float*)d_in[14];
    const float* fc1w = (const float*)d_in[15];
    const float* fc1b = (const float*)d_in[16];
    const float* fc2w = (const float*)d_in[17];
    const float* fc2b = (const float*)d_in[18];
    float* out = (float*)d_out;

    // workspace layout (all 16B-aligned)
    ushortT* h16  = (ushortT*)d_ws;                       // [NN,1024] bf16 (GEMM out)
    ushortT* x16  = h16 + (size_t)NN * 1024;              // [NN,1024] bf16 (GEMM in / agg out)
    float*   x3   = (float*)(x16 + (size_t)NN * 1024);    // [NN,256]  f32
    float*   a_s  = x3 + (size_t)NN * 256;                // [NN,4]
    float*   a_d  = a_s + (size_t)NN * HEADS;             // [NN,4]
    ushortT* wt1  = (ushortT*)(a_d + (size_t)NN * HEADS); // [1024,32]
    ushortT* wt2  = wt1 + 1024 * 32;                      // [1024,1024]
    ushortT* wt3  = wt2 + 1024 * 1024;                    // [256,1024]
    int*   cnt    = (int*)(wt3 + 256 * 1024);             // [NN]
    int*   rowp   = cnt + NN;                             // [NN+1]
    int*   cursor = rowp + NN + 1;                        // [NN]
    int*   col    = cursor + NN;                          // [ETOT]

    // ---- CSR build ----
    hipMemsetAsync(cnt, 0, NN * sizeof(int), stream);
    edge_count_kernel<<<(ETOT + 255) / 256, 256, 0, stream>>>(ei, cnt);
    scan_kernel<<<1, 256, 0, stream>>>(cnt, rowp, cursor);
    edge_fill_kernel<<<(ETOT + 255) / 256, 256, 0, stream>>>(ei, cursor, col);

    // ---- weight + input conversion to bf16 (transposed, K zero-padded) ----
    dim3 cblk(32, 8);
    convert_atom<<<(NN * 32 + 255) / 256, 256, 0, stream>>>(atom, x16);
    convert_wt<<<dim3(32, 1),  cblk, 0, stream>>>(W1, wt1, 23,   1024, 32);
    convert_wt<<<dim3(32, 32), cblk, 0, stream>>>(W2, wt2, 1024, 1024, 1024);
    convert_wt<<<dim3(8, 32),  cblk, 0, stream>>>(W3, wt3, 1024, 256,  1024);

    dim3 blk(256);
    const int gy = (NN + 127) / 128;     // 79
    const int gagg = (NN + 3) / 4;       // 2500 blocks, 4 waves each

    // ---- layer 1: 23(->32) -> 4x256 ----
    hipMemsetAsync(a_s, 0, (size_t)NN * 2 * HEADS * sizeof(float), stream);
    gemm_bf16<<<dim3(8, gy), blk, 0, stream>>>(x16, wt1, h16, as1, ad1, a_s, a_d, HEADS, NN, 1024, 32);
    gat_aggregate_w<<<gagg, blk, 0, stream>>>(h16, a_s, a_d, rowp, col, b1, nullptr, x16, HEADS);

    // ---- layer 2: 1024 -> 4x256 ----
    hipMemsetAsync(a_s, 0, (size_t)NN * 2 * HEADS * sizeof(float), stream);
    gemm_bf16<<<dim3(8, gy), blk, 0, stream>>>(x16, wt2, h16, as2, ad2, a_s, a_d, HEADS, NN, 1024, 1024);
    gat_aggregate_w<<<gagg, blk, 0, stream>>>(h16, a_s, a_d, rowp, col, b2, nullptr, x16, HEADS);

    // ---- layer 3: 1024 -> 1x256 ----
    hipMemsetAsync(a_s, 0, (size_t)NN * 2 * HEADS * sizeof(float), stream);
    gemm_bf16<<<dim3(2, gy), blk, 0, stream>>>(x16, wt3, h16, as3, ad3, a_s, a_d, 1, NN, 256, 1024);
    gat_aggregate_w<<<gagg, blk, 0, stream>>>(h16, a_s, a_d, rowp, col, b3, x3, nullptr, 1);

    // ---- pool + MLP head ----
    pool_mlp<<<NG, blk, 0, stream>>>(x3, batch, fc1w, fc1b, fc2w, fc2b, out);
}